// Round 7
// baseline (120.459 us; speedup 1.0000x reference)
//
#include <hip/hip_runtime.h>
#include <hip/hip_fp16.h>
#include <cstdint>
#include <cmath>

#define HIDDEN   768
#define NPAIR    (HIDDEN / 2)      // 384 (sin,cos) pairs per row
#define SEQ_N    4096
#define LN_EPS   1e-12f
#define N_HI     80                // angle = 64*hi*d_i, hi in [0,80)
#define N_LO     64                // angle = lo*d_i,    lo in [0,64)
#define NBLK     2048              // grid-stride: 4 tokens per wave at B*N=32768

typedef float    f4v __attribute__((ext_vector_type(4)));
typedef _Float16 h4v __attribute__((ext_vector_type(4)));

// ---------------------------------------------------------------------------
// Kernel 1: build the two compact angle-addition tables in d_ws as f16 pairs.
//   T[hi][i]    = (sin, cos)(64*hi * d_i)   hi in [0,80)
//   T[80+lo][i] = (sin, cos)(lo    * d_i)   lo in [0,64)
// d_i = exp(-2i * ln(10000)/HIDDEN).  pe[p] reconstructed via sin(A+B)/
// cos(A+B), p = 64*hi + lo, factors quantized to f16 (~5e-4 abs error).
// Tables = 221 KB -> L2-resident on every XCD.
// ---------------------------------------------------------------------------
__global__ __launch_bounds__(256) void pe_tables_kernel(__half2* __restrict__ T) {
    const int total = (N_HI + N_LO) * NPAIR;
    int idx = blockIdx.x * 256 + threadIdx.x;
    if (idx >= total) return;
    int r = idx / NPAIR;
    int i = idx % NPAIR;
    const float L = logf(10000.0f) / (float)HIDDEN;
    float div = expf(-2.0f * (float)i * L);
    int p = (r < N_HI) ? (r << 6) : (r - N_HI);
    float s, c;
    sincosf((float)p * div, &s, &c);
    T[idx] = __floats2half2_rn(s, c);     // x = sin, y = cos
}

// sin(A+B) = sA*cB + cA*sB ; cos(A+B) = cA*cB - sA*sB
// a = (sinA0, cosA0, sinA1, cosA1), b = (sinB0, cosB0, sinB1, cosB1)  [f16]
__device__ __forceinline__ void pe_acc(float4& x, const h4v a, const h4v b) {
    const float sA0 = (float)a.x, cA0 = (float)a.y, sA1 = (float)a.z, cA1 = (float)a.w;
    const float sB0 = (float)b.x, cB0 = (float)b.y, sB1 = (float)b.z, cB1 = (float)b.w;
    x.x = fmaf(sA0, cB0, fmaf(cA0, sB0, x.x));
    x.y = fmaf(cA0, cB0, fmaf(-sA0, sB0, x.y));
    x.z = fmaf(sA1, cB1, fmaf(cA1, sB1, x.z));
    x.w = fmaf(cA1, cB1, fmaf(-sA1, sB1, x.w));
}

// ---------------------------------------------------------------------------
// Kernel 2: fused embedding-sum + LayerNorm.  One 64-lane wave per token,
// grid-strided 4 tokens/wave.  Token indices are read through readfirstlane
// so they live in SGPRs (s_load, SALU row arithmetic, zero VGPR cost) and the
// NEXT iteration's indices are prefetched in SGPRs, breaking the dependent
// index->gather chain across iterations.  __launch_bounds__(256,8) pins
// VGPR <= 64 (8 waves/SIMD) — the R4 experiment showed crossing 64 VGPR
// halves occupancy and costs ~15 us.
// ---------------------------------------------------------------------------
__global__ __launch_bounds__(256, 8) void emb_ln_kernel(
    const int*     __restrict__ ids,       // (B*N)
    const int*     __restrict__ svec,      // (B*N, 3)
    const int*     __restrict__ tt,        // (B*N)
    const float*   __restrict__ word_emb,  // (VOCAB, HIDDEN)
    const float*   __restrict__ type_emb,  // (2, HIDDEN)
    const float*   __restrict__ gamma,     // (HIDDEN)
    const float*   __restrict__ beta,      // (HIDDEN)
    const __half2* __restrict__ T,         // (N_HI+N_LO, NPAIR) f16 (sin,cos)
    float*         __restrict__ out,       // (B*N, HIDDEN)
    int n_tokens)
{
    const int wave = threadIdx.x >> 6;
    const int lane = threadIdx.x & 63;
    const int nw   = NBLK * 4;                        // total waves in grid
    int tok = blockIdx.x * 4 + wave;
    if (tok >= n_tokens) return;

    // wave-uniform index loads -> SGPRs
    int tu = __builtin_amdgcn_readfirstlane(tok);
    int id = ids[tu], ty = tt[tu];
    int p0 = svec[3 * tu], p1 = svec[3 * tu + 1], p2 = svec[3 * tu + 2];

    for (;;) {
        const int n = tu & (SEQ_N - 1);               // position within sequence

        const float4* wrow = reinterpret_cast<const float4*>(word_emb + (size_t)id * HIDDEN);
        const float4* trow = reinterpret_cast<const float4*>(type_emb + (size_t)ty * HIDDEN);

        #define T1ROW(p) reinterpret_cast<const h4v*>(T + (size_t)((p) >> 6) * NPAIR)
        #define T2ROW(p) reinterpret_cast<const h4v*>(T + (size_t)(N_HI + ((p) & 63)) * NPAIR)
        const h4v* A0 = T1ROW(n),  *B0 = T2ROW(n);
        const h4v* A1 = T1ROW(p0), *B1 = T2ROW(p0);
        const h4v* A2 = T1ROW(p1), *B2 = T2ROW(p1);
        const h4v* A3 = T1ROW(p2), *B3 = T2ROW(p2);
        #undef T1ROW
        #undef T2ROW

        // prefetch next token's indices into SGPRs (scalar loads overlap
        // with this token's gathers and compute)
        const int tnext = tu + nw;                    // wave-uniform
        const bool more = tnext < n_tokens;
        int id_n = 0, ty_n = 0, q0 = 0, q1 = 0, q2 = 0;
        if (more) {
            id_n = ids[tnext]; ty_n = tt[tnext];
            q0 = svec[3 * tnext]; q1 = svec[3 * tnext + 1]; q2 = svec[3 * tnext + 2];
        }

        float4 acc[3];
        float s = 0.0f, ss = 0.0f;

        #pragma unroll
        for (int k = 0; k < 3; ++k) {
            const int d4 = lane + 64 * k;

            float4 w = wrow[d4];
            float4 t = trow[d4];
            h4v a0 = A0[d4], b0 = B0[d4];
            h4v a1 = A1[d4], b1 = B1[d4];
            h4v a2 = A2[d4], b2 = B2[d4];
            h4v a3 = A3[d4], b3 = B3[d4];

            float4 x;
            x.x = w.x + t.x; x.y = w.y + t.y; x.z = w.z + t.z; x.w = w.w + t.w;
            pe_acc(x, a0, b0);
            pe_acc(x, a1, b1);
            pe_acc(x, a2, b2);
            pe_acc(x, a3, b3);

            acc[k] = x;
            s  += x.x + x.y + x.z + x.w;
            ss += x.x * x.x + x.y * x.y + x.z * x.z + x.w * x.w;
        }

        #pragma unroll
        for (int off = 1; off < 64; off <<= 1) {
            s  += __shfl_xor(s,  off);
            ss += __shfl_xor(ss, off);
        }

        const float mean = s * (1.0f / (float)HIDDEN);
        const float var  = ss * (1.0f / (float)HIDDEN) - mean * mean;
        const float inv  = rsqrtf(var + LN_EPS);

        const float4* g4 = reinterpret_cast<const float4*>(gamma);
        const float4* b4 = reinterpret_cast<const float4*>(beta);
        float4* orow = reinterpret_cast<float4*>(out + (size_t)tu * HIDDEN);

        #pragma unroll
        for (int k = 0; k < 3; ++k) {
            const int d4 = lane + 64 * k;
            const float4 g = g4[d4];
            const float4 b = b4[d4];
            const float4 x = acc[k];
            float4 r;
            r.x = (x.x - mean) * inv * g.x + b.x;
            r.y = (x.y - mean) * inv * g.y + b.y;
            r.z = (x.z - mean) * inv * g.z + b.z;
            r.w = (x.w - mean) * inv * g.w + b.w;
            orow[d4] = r;
        }

        if (!more) break;
        tu = tnext; id = id_n; ty = ty_n; p0 = q0; p1 = q1; p2 = q2;
    }
}

extern "C" void kernel_launch(void* const* d_in, const int* in_sizes, int n_in,
                              void* d_out, int out_size, void* d_ws, size_t ws_size,
                              hipStream_t stream) {
    const int*   ids      = (const int*)d_in[0];   // input_ids      (B*N)
    const int*   svec     = (const int*)d_in[1];   // tok_struct_vec (B*N*3)
    const int*   tt       = (const int*)d_in[2];   // token_type_ids (B*N)
    const float* word_emb = (const float*)d_in[3]; // (VOCAB, HIDDEN)
    const float* type_emb = (const float*)d_in[4]; // (2, HIDDEN)
    const float* gamma    = (const float*)d_in[5]; // (HIDDEN)
    const float* beta     = (const float*)d_in[6]; // (HIDDEN)
    float*       out      = (float*)d_out;

    const int n_tokens = in_sizes[0];

    // Workspace: 144 rows x 384 __half2 = 221 KB.
    __half2* T = (__half2*)d_ws;
    const int total_tab = (N_HI + N_LO) * NPAIR;
    pe_tables_kernel<<<(total_tab + 255) / 256, 256, 0, stream>>>(T);
    emb_ln_kernel<<<NBLK, 256, 0, stream>>>(
        ids, svec, tt, word_emb, type_emb, gamma, beta, T, out, n_tokens);
}

// Round 8
// 51.343 us; speedup vs baseline: 2.3462x; 2.3462x over previous
//
#include <hip/hip_runtime.h>
#include <hip/hip_fp16.h>
#include <cstdint>
#include <cmath>

#define HIDDEN   768
#define NPAIR    (HIDDEN / 2)      // 384 (sin,cos) pairs per row
#define SEQ_N    4096
#define LN_EPS   1e-12f
#define N_HI     80                // angle = 64*hi*d_i, hi in [0,80)
#define N_LO     64                // angle = lo*d_i,    lo in [0,64)
#define NBLK     2048              // grid-stride: 4 tokens per wave at B*N=32768

typedef float    f4v __attribute__((ext_vector_type(4)));
typedef _Float16 h4v __attribute__((ext_vector_type(4)));

// ---------------------------------------------------------------------------
// Kernel 1: build the two compact angle-addition tables in d_ws as f16 pairs.
//   T[hi][i]    = (sin, cos)(64*hi * d_i)   hi in [0,80)
//   T[80+lo][i] = (sin, cos)(lo    * d_i)   lo in [0,64)
// d_i = exp(-2i * ln(10000)/HIDDEN).  pe[p] reconstructed via sin(A+B)/
// cos(A+B), p = 64*hi + lo, factors quantized to f16 (~5e-4 abs error).
// Tables = 221 KB -> L2-resident on every XCD.
// ---------------------------------------------------------------------------
__global__ __launch_bounds__(256) void pe_tables_kernel(__half2* __restrict__ T) {
    const int total = (N_HI + N_LO) * NPAIR;
    int idx = blockIdx.x * 256 + threadIdx.x;
    if (idx >= total) return;
    int r = idx / NPAIR;
    int i = idx % NPAIR;
    const float L = logf(10000.0f) / (float)HIDDEN;
    float div = expf(-2.0f * (float)i * L);
    int p = (r < N_HI) ? (r << 6) : (r - N_HI);
    float s, c;
    sincosf((float)p * div, &s, &c);
    T[idx] = __floats2half2_rn(s, c);     // x = sin, y = cos
}

// sin(A+B) = sA*cB + cA*sB ; cos(A+B) = cA*cB - sA*sB
// a = (sinA0, cosA0, sinA1, cosA1), b = (sinB0, cosB0, sinB1, cosB1)  [f16]
__device__ __forceinline__ void pe_acc(float4& x, const h4v a, const h4v b) {
    const float sA0 = (float)a.x, cA0 = (float)a.y, sA1 = (float)a.z, cA1 = (float)a.w;
    const float sB0 = (float)b.x, cB0 = (float)b.y, sB1 = (float)b.z, cB1 = (float)b.w;
    x.x = fmaf(sA0, cB0, fmaf(cA0, sB0, x.x));
    x.y = fmaf(cA0, cB0, fmaf(-sA0, sB0, x.y));
    x.z = fmaf(sA1, cB1, fmaf(cA1, sB1, x.z));
    x.w = fmaf(cA1, cB1, fmaf(-sA1, sB1, x.w));
}

// ---------------------------------------------------------------------------
// Kernel 2: fused embedding-sum + LayerNorm.  One 64-lane wave per token,
// grid-strided 4 tokens/wave (2048 blocks — removes the 8192-block dispatch
// churn that capped R6 occupancy at 37%).  Token indices live in SGPRs via
// readfirstlane (s_load + SALU) and the NEXT iteration's indices are
// prefetched in SGPRs, breaking the index->gather dependent chain.
// __launch_bounds__(256, 4): VGPR cap 128 — R7 proved that forcing 8
// waves/EU (VGPR=32) causes spills (FETCH 52->223 MB, dur 2.3x); the body
// needs ~15 live float4s, so let the compiler land at its natural ~64-90.
// ---------------------------------------------------------------------------
__global__ __launch_bounds__(256, 4) void emb_ln_kernel(
    const int*     __restrict__ ids,       // (B*N)
    const int*     __restrict__ svec,      // (B*N, 3)
    const int*     __restrict__ tt,        // (B*N)
    const float*   __restrict__ word_emb,  // (VOCAB, HIDDEN)
    const float*   __restrict__ type_emb,  // (2, HIDDEN)
    const float*   __restrict__ gamma,     // (HIDDEN)
    const float*   __restrict__ beta,      // (HIDDEN)
    const __half2* __restrict__ T,         // (N_HI+N_LO, NPAIR) f16 (sin,cos)
    float*         __restrict__ out,       // (B*N, HIDDEN)
    int n_tokens)
{
    const int wave = threadIdx.x >> 6;
    const int lane = threadIdx.x & 63;
    const int nw   = NBLK * 4;                        // total waves in grid
    int tok = blockIdx.x * 4 + wave;
    if (tok >= n_tokens) return;

    // wave-uniform index loads -> SGPRs
    int tu = __builtin_amdgcn_readfirstlane(tok);
    int id = ids[tu], ty = tt[tu];
    int p0 = svec[3 * tu], p1 = svec[3 * tu + 1], p2 = svec[3 * tu + 2];

    for (;;) {
        const int n = tu & (SEQ_N - 1);               // position within sequence

        const float4* wrow = reinterpret_cast<const float4*>(word_emb + (size_t)id * HIDDEN);
        const float4* trow = reinterpret_cast<const float4*>(type_emb + (size_t)ty * HIDDEN);

        #define T1ROW(p) reinterpret_cast<const h4v*>(T + (size_t)((p) >> 6) * NPAIR)
        #define T2ROW(p) reinterpret_cast<const h4v*>(T + (size_t)(N_HI + ((p) & 63)) * NPAIR)
        const h4v* A0 = T1ROW(n),  *B0 = T2ROW(n);
        const h4v* A1 = T1ROW(p0), *B1 = T2ROW(p0);
        const h4v* A2 = T1ROW(p1), *B2 = T2ROW(p1);
        const h4v* A3 = T1ROW(p2), *B3 = T2ROW(p2);
        #undef T1ROW
        #undef T2ROW

        // prefetch next token's indices into SGPRs (scalar loads overlap
        // with this token's gathers and compute)
        const int tnext = tu + nw;                    // wave-uniform
        const bool more = tnext < n_tokens;
        int id_n = 0, ty_n = 0, q0 = 0, q1 = 0, q2 = 0;
        if (more) {
            id_n = ids[tnext]; ty_n = tt[tnext];
            q0 = svec[3 * tnext]; q1 = svec[3 * tnext + 1]; q2 = svec[3 * tnext + 2];
        }

        float4 acc[3];
        float s = 0.0f, ss = 0.0f;

        #pragma unroll
        for (int k = 0; k < 3; ++k) {
            const int d4 = lane + 64 * k;

            float4 w = wrow[d4];
            float4 t = trow[d4];
            h4v a0 = A0[d4], b0 = B0[d4];
            h4v a1 = A1[d4], b1 = B1[d4];
            h4v a2 = A2[d4], b2 = B2[d4];
            h4v a3 = A3[d4], b3 = B3[d4];

            float4 x;
            x.x = w.x + t.x; x.y = w.y + t.y; x.z = w.z + t.z; x.w = w.w + t.w;
            pe_acc(x, a0, b0);
            pe_acc(x, a1, b1);
            pe_acc(x, a2, b2);
            pe_acc(x, a3, b3);

            acc[k] = x;
            s  += x.x + x.y + x.z + x.w;
            ss += x.x * x.x + x.y * x.y + x.z * x.z + x.w * x.w;
        }

        #pragma unroll
        for (int off = 1; off < 64; off <<= 1) {
            s  += __shfl_xor(s,  off);
            ss += __shfl_xor(ss, off);
        }

        const float mean = s * (1.0f / (float)HIDDEN);
        const float var  = ss * (1.0f / (float)HIDDEN) - mean * mean;
        const float inv  = rsqrtf(var + LN_EPS);

        const float4* g4 = reinterpret_cast<const float4*>(gamma);
        const float4* b4 = reinterpret_cast<const float4*>(beta);
        float4* orow = reinterpret_cast<float4*>(out + (size_t)tu * HIDDEN);

        #pragma unroll
        for (int k = 0; k < 3; ++k) {
            const int d4 = lane + 64 * k;
            const float4 g = g4[d4];
            const float4 b = b4[d4];
            const float4 x = acc[k];
            float4 r;
            r.x = (x.x - mean) * inv * g.x + b.x;
            r.y = (x.y - mean) * inv * g.y + b.y;
            r.z = (x.z - mean) * inv * g.z + b.z;
            r.w = (x.w - mean) * inv * g.w + b.w;
            orow[d4] = r;
        }

        if (!more) break;
        tu = tnext; id = id_n; ty = ty_n; p0 = q0; p1 = q1; p2 = q2;
    }
}

extern "C" void kernel_launch(void* const* d_in, const int* in_sizes, int n_in,
                              void* d_out, int out_size, void* d_ws, size_t ws_size,
                              hipStream_t stream) {
    const int*   ids      = (const int*)d_in[0];   // input_ids      (B*N)
    const int*   svec     = (const int*)d_in[1];   // tok_struct_vec (B*N*3)
    const int*   tt       = (const int*)d_in[2];   // token_type_ids (B*N)
    const float* word_emb = (const float*)d_in[3]; // (VOCAB, HIDDEN)
    const float* type_emb = (const float*)d_in[4]; // (2, HIDDEN)
    const float* gamma    = (const float*)d_in[5]; // (HIDDEN)
    const float* beta     = (const float*)d_in[6]; // (HIDDEN)
    float*       out      = (float*)d_out;

    const int n_tokens = in_sizes[0];

    // Workspace: 144 rows x 384 __half2 = 221 KB.
    __half2* T = (__half2*)d_ws;
    const int total_tab = (N_HI + N_LO) * NPAIR;
    pe_tables_kernel<<<(total_tab + 255) / 256, 256, 0, stream>>>(T);
    emb_ln_kernel<<<NBLK, 256, 0, stream>>>(
        ids, svec, tt, word_emb, type_emb, gamma, beta, T, out, n_tokens);
}

// Round 9
// 50.908 us; speedup vs baseline: 2.3662x; 1.0085x over previous
//
#include <hip/hip_runtime.h>
#include <hip/hip_fp16.h>
#include <cstdint>
#include <cmath>

#define HIDDEN   768
#define NPAIR    (HIDDEN / 2)      // 384 (sin,cos) pairs per row
#define SEQ_N    4096
#define LN_EPS   1e-12f
#define N_HI     80                // angle = 64*hi*d_i, hi in [0,80)
#define N_LO     64                // angle = lo*d_i,    lo in [0,64)
#define NBLK     2048              // grid-stride: 4 tokens per wave at B*N=32768

typedef float    f4v __attribute__((ext_vector_type(4)));
typedef _Float16 h4v __attribute__((ext_vector_type(4)));

// ---------------------------------------------------------------------------
// Kernel 1: build the two compact angle-addition tables in d_ws as f16 pairs.
//   T[hi][i]    = (sin, cos)(64*hi * d_i)   hi in [0,80)
//   T[80+lo][i] = (sin, cos)(lo    * d_i)   lo in [0,64)
// d_i = exp(-2i * ln(10000)/HIDDEN).  pe[p] reconstructed via sin(A+B)/
// cos(A+B), p = 64*hi + lo, factors quantized to f16 (~5e-4 abs error).
// Tables = 221 KB -> L2-resident on every XCD.
// ---------------------------------------------------------------------------
__global__ __launch_bounds__(256) void pe_tables_kernel(__half2* __restrict__ T) {
    const int total = (N_HI + N_LO) * NPAIR;
    int idx = blockIdx.x * 256 + threadIdx.x;
    if (idx >= total) return;
    int r = idx / NPAIR;
    int i = idx % NPAIR;
    const float L = logf(10000.0f) / (float)HIDDEN;
    float div = expf(-2.0f * (float)i * L);
    int p = (r < N_HI) ? (r << 6) : (r - N_HI);
    float s, c;
    sincosf((float)p * div, &s, &c);
    T[idx] = __floats2half2_rn(s, c);     // x = sin, y = cos
}

// sin(A+B) = sA*cB + cA*sB ; cos(A+B) = cA*cB - sA*sB
// a = (sinA0, cosA0, sinA1, cosA1), b = (sinB0, cosB0, sinB1, cosB1)  [f16]
__device__ __forceinline__ void pe_acc(float4& x, const h4v a, const h4v b) {
    const float sA0 = (float)a.x, cA0 = (float)a.y, sA1 = (float)a.z, cA1 = (float)a.w;
    const float sB0 = (float)b.x, cB0 = (float)b.y, sB1 = (float)b.z, cB1 = (float)b.w;
    x.x = fmaf(sA0, cB0, fmaf(cA0, sB0, x.x));
    x.y = fmaf(cA0, cB0, fmaf(-sA0, sB0, x.y));
    x.z = fmaf(sA1, cB1, fmaf(cA1, sB1, x.z));
    x.w = fmaf(cA1, cB1, fmaf(-sA1, sB1, x.w));
}

// ---------------------------------------------------------------------------
// Kernel 2: fused embedding-sum + LayerNorm.  One 64-lane wave per token,
// grid-strided 4 tokens/wave (2048 blocks).  Software pipeline:
//   - indices prefetched TWO tokens ahead (SGPR s_loads),
//   - the word-embedding row (the only L3/HBM-latency gather) is loaded ONE
//     token ahead into registers, so iteration i's compute covers iteration
//     i+1's gather latency.
// Table reads (L2-resident, ~200cy) stay same-iteration — TLP covers them.
// Output uses non-temporal stores (pure 100 MB stream; keep it from
// contending L2/L3 with the word table).
// __launch_bounds__(256,4): VGPR cap 128.  R7 proved a 32-VGPR force spills
// (FETCH 52->223 MB, 2.3x dur); the double word-stage needs ~110-125.
// ---------------------------------------------------------------------------
__global__ __launch_bounds__(256, 4) void emb_ln_kernel(
    const int*     __restrict__ ids,       // (B*N)
    const int*     __restrict__ svec,      // (B*N, 3)
    const int*     __restrict__ tt,        // (B*N)
    const float*   __restrict__ word_emb,  // (VOCAB, HIDDEN)
    const float*   __restrict__ type_emb,  // (2, HIDDEN)
    const float*   __restrict__ gamma,     // (HIDDEN)
    const float*   __restrict__ beta,      // (HIDDEN)
    const __half2* __restrict__ T,         // (N_HI+N_LO, NPAIR) f16 (sin,cos)
    float*         __restrict__ out,       // (B*N, HIDDEN)
    int n_tokens)
{
    const int wave = threadIdx.x >> 6;
    const int lane = threadIdx.x & 63;
    const int nw   = NBLK * 4;                        // total waves in grid
    int tu = __builtin_amdgcn_readfirstlane(blockIdx.x * 4 + wave);
    if (tu >= n_tokens) return;

    // ---- token i indices (SGPR) ----
    int ty_c = tt[tu];
    int p0_c = svec[3 * tu], p1_c = svec[3 * tu + 1], p2_c = svec[3 * tu + 2];
    const int id_c = ids[tu];

    // ---- token i+1 indices (SGPR) ----
    int  tu_n  = tu + nw;
    bool more1 = tu_n < n_tokens;
    int id_n = 0, ty_n = 0, p0_n = 0, p1_n = 0, p2_n = 0;
    if (more1) {
        id_n = ids[tu_n]; ty_n = tt[tu_n];
        p0_n = svec[3 * tu_n]; p1_n = svec[3 * tu_n + 1]; p2_n = svec[3 * tu_n + 2];
    }

    // ---- preamble: stage token i's word row ----
    const float4* wr0 = reinterpret_cast<const float4*>(word_emb + (size_t)id_c * HIDDEN);
    float4 w0 = wr0[lane], w1 = wr0[lane + 64], w2 = wr0[lane + 128];

    for (;;) {
        // ---- issue token i+1's word-row gather (id already in SGPR) ----
        float4 nw0, nw1, nw2;
        if (more1) {
            const float4* wr = reinterpret_cast<const float4*>(word_emb + (size_t)id_n * HIDDEN);
            nw0 = wr[lane]; nw1 = wr[lane + 64]; nw2 = wr[lane + 128];
        }

        // ---- prefetch token i+2 indices (SGPR s_loads) ----
        const int  tu_2  = tu_n + nw;
        const bool more2 = more1 && (tu_2 < n_tokens);
        int id_2 = 0, ty_2 = 0, p0_2 = 0, p1_2 = 0, p2_2 = 0;
        if (more2) {
            id_2 = ids[tu_2]; ty_2 = tt[tu_2];
            p0_2 = svec[3 * tu_2]; p1_2 = svec[3 * tu_2 + 1]; p2_2 = svec[3 * tu_2 + 2];
        }

        // ---- compute token i ----
        const int n = tu & (SEQ_N - 1);
        const float4* trow = reinterpret_cast<const float4*>(type_emb + (size_t)ty_c * HIDDEN);

        #define T1ROW(p) reinterpret_cast<const h4v*>(T + (size_t)((p) >> 6) * NPAIR)
        #define T2ROW(p) reinterpret_cast<const h4v*>(T + (size_t)(N_HI + ((p) & 63)) * NPAIR)
        const h4v* A0 = T1ROW(n),    *B0 = T2ROW(n);
        const h4v* A1 = T1ROW(p0_c), *B1 = T2ROW(p0_c);
        const h4v* A2 = T1ROW(p1_c), *B2 = T2ROW(p1_c);
        const h4v* A3 = T1ROW(p2_c), *B3 = T2ROW(p2_c);
        #undef T1ROW
        #undef T2ROW

        float4 acc[3];
        float s = 0.0f, ss = 0.0f;
        const float4 wcur[3] = { w0, w1, w2 };

        #pragma unroll
        for (int k = 0; k < 3; ++k) {
            const int d4 = lane + 64 * k;

            float4 t = trow[d4];
            h4v a0 = A0[d4], b0 = B0[d4];
            h4v a1 = A1[d4], b1 = B1[d4];
            h4v a2 = A2[d4], b2 = B2[d4];
            h4v a3 = A3[d4], b3 = B3[d4];

            float4 x;
            x.x = wcur[k].x + t.x; x.y = wcur[k].y + t.y;
            x.z = wcur[k].z + t.z; x.w = wcur[k].w + t.w;
            pe_acc(x, a0, b0);
            pe_acc(x, a1, b1);
            pe_acc(x, a2, b2);
            pe_acc(x, a3, b3);

            acc[k] = x;
            s  += x.x + x.y + x.z + x.w;
            ss += x.x * x.x + x.y * x.y + x.z * x.z + x.w * x.w;
        }

        #pragma unroll
        for (int off = 1; off < 64; off <<= 1) {
            s  += __shfl_xor(s,  off);
            ss += __shfl_xor(ss, off);
        }

        const float mean = s * (1.0f / (float)HIDDEN);
        const float var  = ss * (1.0f / (float)HIDDEN) - mean * mean;
        const float inv  = rsqrtf(var + LN_EPS);

        const float4* g4 = reinterpret_cast<const float4*>(gamma);
        const float4* b4 = reinterpret_cast<const float4*>(beta);
        f4v* orow = reinterpret_cast<f4v*>(out + (size_t)tu * HIDDEN);

        #pragma unroll
        for (int k = 0; k < 3; ++k) {
            const int d4 = lane + 64 * k;
            const float4 g = g4[d4];
            const float4 b = b4[d4];
            const float4 x = acc[k];
            f4v r;
            r.x = (x.x - mean) * inv * g.x + b.x;
            r.y = (x.y - mean) * inv * g.y + b.y;
            r.z = (x.z - mean) * inv * g.z + b.z;
            r.w = (x.w - mean) * inv * g.w + b.w;
            __builtin_nontemporal_store(r, &orow[d4]);
        }

        if (!more1) break;
        // rotate pipeline
        tu = tu_n;  ty_c = ty_n;  p0_c = p0_n;  p1_c = p1_n;  p2_c = p2_n;
        tu_n = tu_2;  more1 = more2;
        id_n = id_2;  ty_n = ty_2;  p0_n = p0_2;  p1_n = p1_2;  p2_n = p2_2;
        w0 = nw0;  w1 = nw1;  w2 = nw2;
    }
}

extern "C" void kernel_launch(void* const* d_in, const int* in_sizes, int n_in,
                              void* d_out, int out_size, void* d_ws, size_t ws_size,
                              hipStream_t stream) {
    const int*   ids      = (const int*)d_in[0];   // input_ids      (B*N)
    const int*   svec     = (const int*)d_in[1];   // tok_struct_vec (B*N*3)
    const int*   tt       = (const int*)d_in[2];   // token_type_ids (B*N)
    const float* word_emb = (const float*)d_in[3]; // (VOCAB, HIDDEN)
    const float* type_emb = (const float*)d_in[4]; // (2, HIDDEN)
    const float* gamma    = (const float*)d_in[5]; // (HIDDEN)
    const float* beta     = (const float*)d_in[6]; // (HIDDEN)
    float*       out      = (float*)d_out;

    const int n_tokens = in_sizes[0];

    // Workspace: 144 rows x 384 __half2 = 221 KB.
    __half2* T = (__half2*)d_ws;
    const int total_tab = (N_HI + N_LO) * NPAIR;
    pe_tables_kernel<<<(total_tab + 255) / 256, 256, 0, stream>>>(T);
    emb_ln_kernel<<<NBLK, 256, 0, stream>>>(
        ids, svec, tt, word_emb, type_emb, gamma, beta, T, out, n_tokens);
}

// Round 10
// 48.899 us; speedup vs baseline: 2.4634x; 1.0411x over previous
//
#include <hip/hip_runtime.h>
#include <hip/hip_fp16.h>
#include <cstdint>
#include <cmath>

#define HIDDEN   768
#define NPAIR    (HIDDEN / 2)      // 384 (sin,cos) pairs per row
#define SEQ_N    4096
#define LN_EPS   1e-12f
#define N_HI     80                // angle = 64*hi*d_i, hi in [0,80)
#define N_LO     64                // angle = lo*d_i,    lo in [0,64)
#define NBLK     2048              // grid-stride: 4 tokens per wave at B*N=32768

typedef float    f4v __attribute__((ext_vector_type(4)));
typedef _Float16 h4v __attribute__((ext_vector_type(4)));

// ---------------------------------------------------------------------------
// Kernel 1: build the two compact angle-addition tables in d_ws as f16 pairs.
//   T[hi][i]    = (sin, cos)(64*hi * d_i)   hi in [0,80)
//   T[80+lo][i] = (sin, cos)(lo    * d_i)   lo in [0,64)
// d_i = exp(-2i * ln(10000)/HIDDEN).  pe[p] reconstructed via sin(A+B)/
// cos(A+B), p = 64*hi + lo, factors quantized to f16 (~5e-4 abs error).
// Tables = 221 KB -> L2-resident on every XCD.
// ---------------------------------------------------------------------------
__global__ __launch_bounds__(256) void pe_tables_kernel(__half2* __restrict__ T) {
    const int total = (N_HI + N_LO) * NPAIR;
    int idx = blockIdx.x * 256 + threadIdx.x;
    if (idx >= total) return;
    int r = idx / NPAIR;
    int i = idx % NPAIR;
    const float L = logf(10000.0f) / (float)HIDDEN;
    float div = expf(-2.0f * (float)i * L);
    int p = (r < N_HI) ? (r << 6) : (r - N_HI);
    float s, c;
    sincosf((float)p * div, &s, &c);
    T[idx] = __floats2half2_rn(s, c);     // x = sin, y = cos
}

// sin(A+B) = sA*cB + cA*sB ; cos(A+B) = cA*cB - sA*sB
// a = (sinA0, cosA0, sinA1, cosA1), b = (sinB0, cosB0, sinB1, cosB1)  [f16]
__device__ __forceinline__ void pe_acc(float4& x, const h4v a, const h4v b) {
    const float sA0 = (float)a.x, cA0 = (float)a.y, sA1 = (float)a.z, cA1 = (float)a.w;
    const float sB0 = (float)b.x, cB0 = (float)b.y, sB1 = (float)b.z, cB1 = (float)b.w;
    x.x = fmaf(sA0, cB0, fmaf(cA0, sB0, x.x));
    x.y = fmaf(cA0, cB0, fmaf(-sA0, sB0, x.y));
    x.z = fmaf(sA1, cB1, fmaf(cA1, sB1, x.z));
    x.w = fmaf(cA1, cB1, fmaf(-sA1, sB1, x.w));
}

// ---------------------------------------------------------------------------
// Kernel 2: fused embedding-sum + LayerNorm.  One 64-lane wave per token,
// grid-strided 4 tokens/wave (2048 blocks).  Indices prefetched one token
// ahead in SGPRs (readfirstlane -> s_load).  gamma/beta are hoisted into
// per-wave registers OUTSIDE the loop: they were 6 KB/token of L1 read
// traffic (25% of the per-token 24 KB), and L1 port BW (~64 B/cyc/CU,
// shared by 4 SIMDs) is the saturated resource — per-CU L1 time was
// ~20 us and TLP-insensitive (R6 8w vs R8 4w both ~51-53 us).
// R9's word-row double-stage was neutral -> reverted (frees 12 VGPR for
// the gamma/beta cache; stay under the 128 cap, no spill — R7 lesson).
// ---------------------------------------------------------------------------
__global__ __launch_bounds__(256, 4) void emb_ln_kernel(
    const int*     __restrict__ ids,       // (B*N)
    const int*     __restrict__ svec,      // (B*N, 3)
    const int*     __restrict__ tt,        // (B*N)
    const float*   __restrict__ word_emb,  // (VOCAB, HIDDEN)
    const float*   __restrict__ type_emb,  // (2, HIDDEN)
    const float*   __restrict__ gamma,     // (HIDDEN)
    const float*   __restrict__ beta,      // (HIDDEN)
    const __half2* __restrict__ T,         // (N_HI+N_LO, NPAIR) f16 (sin,cos)
    float*         __restrict__ out,       // (B*N, HIDDEN)
    int n_tokens)
{
    const int wave = threadIdx.x >> 6;
    const int lane = threadIdx.x & 63;
    const int nw   = NBLK * 4;                        // total waves in grid
    int tu = __builtin_amdgcn_readfirstlane(blockIdx.x * 4 + wave);
    if (tu >= n_tokens) return;

    // ---- per-wave register cache: gamma, beta (reused across all tokens) ----
    const float4* g4 = reinterpret_cast<const float4*>(gamma);
    const float4* b4 = reinterpret_cast<const float4*>(beta);
    float4 gc[3], bc[3];
    #pragma unroll
    for (int k = 0; k < 3; ++k) {
        gc[k] = g4[lane + 64 * k];
        bc[k] = b4[lane + 64 * k];
    }

    // ---- current token indices (SGPR via wave-uniform address) ----
    int id = ids[tu], ty = tt[tu];
    int p0 = svec[3 * tu], p1 = svec[3 * tu + 1], p2 = svec[3 * tu + 2];

    for (;;) {
        const int n = tu & (SEQ_N - 1);               // position within sequence

        const float4* wrow = reinterpret_cast<const float4*>(word_emb + (size_t)id * HIDDEN);
        const float4* trow = reinterpret_cast<const float4*>(type_emb + (size_t)ty * HIDDEN);

        #define T1ROW(p) reinterpret_cast<const h4v*>(T + (size_t)((p) >> 6) * NPAIR)
        #define T2ROW(p) reinterpret_cast<const h4v*>(T + (size_t)(N_HI + ((p) & 63)) * NPAIR)
        const h4v* A0 = T1ROW(n),  *B0 = T2ROW(n);
        const h4v* A1 = T1ROW(p0), *B1 = T2ROW(p0);
        const h4v* A2 = T1ROW(p1), *B2 = T2ROW(p1);
        const h4v* A3 = T1ROW(p2), *B3 = T2ROW(p2);
        #undef T1ROW
        #undef T2ROW

        // prefetch next token's indices into SGPRs (overlaps with compute)
        const int tnext = tu + nw;                    // wave-uniform
        const bool more = tnext < n_tokens;
        int id_n = 0, ty_n = 0, q0 = 0, q1 = 0, q2 = 0;
        if (more) {
            id_n = ids[tnext]; ty_n = tt[tnext];
            q0 = svec[3 * tnext]; q1 = svec[3 * tnext + 1]; q2 = svec[3 * tnext + 2];
        }

        float4 acc[3];
        float s = 0.0f, ss = 0.0f;

        #pragma unroll
        for (int k = 0; k < 3; ++k) {
            const int d4 = lane + 64 * k;

            float4 w = wrow[d4];
            float4 t = trow[d4];
            h4v a0 = A0[d4], b0 = B0[d4];
            h4v a1 = A1[d4], b1 = B1[d4];
            h4v a2 = A2[d4], b2 = B2[d4];
            h4v a3 = A3[d4], b3 = B3[d4];

            float4 x;
            x.x = w.x + t.x; x.y = w.y + t.y; x.z = w.z + t.z; x.w = w.w + t.w;
            pe_acc(x, a0, b0);
            pe_acc(x, a1, b1);
            pe_acc(x, a2, b2);
            pe_acc(x, a3, b3);

            acc[k] = x;
            s  += x.x + x.y + x.z + x.w;
            ss += x.x * x.x + x.y * x.y + x.z * x.z + x.w * x.w;
        }

        #pragma unroll
        for (int off = 1; off < 64; off <<= 1) {
            s  += __shfl_xor(s,  off);
            ss += __shfl_xor(ss, off);
        }

        const float mean = s * (1.0f / (float)HIDDEN);
        const float var  = ss * (1.0f / (float)HIDDEN) - mean * mean;
        const float inv  = rsqrtf(var + LN_EPS);

        f4v* orow = reinterpret_cast<f4v*>(out + (size_t)tu * HIDDEN);
        #pragma unroll
        for (int k = 0; k < 3; ++k) {
            const int d4 = lane + 64 * k;
            const float4 x = acc[k];
            f4v r;
            r.x = (x.x - mean) * inv * gc[k].x + bc[k].x;
            r.y = (x.y - mean) * inv * gc[k].y + bc[k].y;
            r.z = (x.z - mean) * inv * gc[k].z + bc[k].z;
            r.w = (x.w - mean) * inv * gc[k].w + bc[k].w;
            __builtin_nontemporal_store(r, &orow[d4]);
        }

        if (!more) break;
        tu = tnext; id = id_n; ty = ty_n; p0 = q0; p1 = q1; p2 = q2;
    }
}

extern "C" void kernel_launch(void* const* d_in, const int* in_sizes, int n_in,
                              void* d_out, int out_size, void* d_ws, size_t ws_size,
                              hipStream_t stream) {
    const int*   ids      = (const int*)d_in[0];   // input_ids      (B*N)
    const int*   svec     = (const int*)d_in[1];   // tok_struct_vec (B*N*3)
    const int*   tt       = (const int*)d_in[2];   // token_type_ids (B*N)
    const float* word_emb = (const float*)d_in[3]; // (VOCAB, HIDDEN)
    const float* type_emb = (const float*)d_in[4]; // (2, HIDDEN)
    const float* gamma    = (const float*)d_in[5]; // (HIDDEN)
    const float* beta     = (const float*)d_in[6]; // (HIDDEN)
    float*       out      = (float*)d_out;

    const int n_tokens = in_sizes[0];

    // Workspace: 144 rows x 384 __half2 = 221 KB.
    __half2* T = (__half2*)d_ws;
    const int total_tab = (N_HI + N_LO) * NPAIR;
    pe_tables_kernel<<<(total_tab + 255) / 256, 256, 0, stream>>>(T);
    emb_ln_kernel<<<NBLK, 256, 0, stream>>>(
        ids, svec, tt, word_emb, type_emb, gamma, beta, T, out, n_tokens);
}

// Round 11
// 46.934 us; speedup vs baseline: 2.5665x; 1.0419x over previous
//
#include <hip/hip_runtime.h>
#include <hip/hip_fp16.h>
#include <cstdint>
#include <cmath>

#define HIDDEN   768
#define NPAIR    (HIDDEN / 2)      // 384 (sin,cos) pairs per row
#define SEQ_N    4096
#define LN_EPS   1e-12f
#define N_HI     80                // angle = 64*hi*d_i, hi in [0,80)
#define N_LO     64                // angle = lo*d_i,    lo in [0,64)
#define NBLK     2048              // grid-stride: 4 tokens per wave at B*N=32768

typedef float    f4v __attribute__((ext_vector_type(4)));
typedef _Float16 h4v __attribute__((ext_vector_type(4)));

// ---------------------------------------------------------------------------
// Kernel 1: build the two compact angle-addition tables in d_ws as f16 pairs.
//   T[hi][i]    = (sin, cos)(64*hi * d_i)   hi in [0,80)
//   T[80+lo][i] = (sin, cos)(lo    * d_i)   lo in [0,64)
// d_i = exp(-2i * ln(10000)/HIDDEN).  pe[p] reconstructed via sin(A+B)/
// cos(A+B), p = 64*hi + lo, factors quantized to f16 (~5e-4 abs error).
// Tables = 221 KB -> L2-resident on every XCD.
// ---------------------------------------------------------------------------
__global__ __launch_bounds__(256) void pe_tables_kernel(__half2* __restrict__ T) {
    const int total = (N_HI + N_LO) * NPAIR;
    int idx = blockIdx.x * 256 + threadIdx.x;
    if (idx >= total) return;
    int r = idx / NPAIR;
    int i = idx % NPAIR;
    const float L = logf(10000.0f) / (float)HIDDEN;
    float div = expf(-2.0f * (float)i * L);
    int p = (r < N_HI) ? (r << 6) : (r - N_HI);
    float s, c;
    sincosf((float)p * div, &s, &c);
    T[idx] = __floats2half2_rn(s, c);     // x = sin, y = cos
}

// sin(A+B) = sA*cB + cA*sB ; cos(A+B) = cA*cB - sA*sB
// a = (sinA0, cosA0, sinA1, cosA1), b = (sinB0, cosB0, sinB1, cosB1)  [f16]
// (float)h * (float)h + float matches v_fma_mix_f32 — no explicit cvts.
__device__ __forceinline__ void pe_acc(float4& x, const h4v a, const h4v b) {
    const float sA0 = (float)a.x, cA0 = (float)a.y, sA1 = (float)a.z, cA1 = (float)a.w;
    const float sB0 = (float)b.x, cB0 = (float)b.y, sB1 = (float)b.z, cB1 = (float)b.w;
    x.x = fmaf(sA0, cB0, fmaf(cA0, sB0, x.x));
    x.y = fmaf(cA0, cB0, fmaf(-sA0, sB0, x.y));
    x.z = fmaf(sA1, cB1, fmaf(cA1, sB1, x.z));
    x.w = fmaf(cA1, cB1, fmaf(-sA1, sB1, x.w));
}

// ---------------------------------------------------------------------------
// Kernel 2: fused embedding-sum + LayerNorm.  One 64-lane wave per token,
// grid-strided 4 tokens/wave (2048 blocks).  Indices prefetched one token
// ahead in SGPRs (readfirstlane -> s_load).
// NEW (R11): type0/type1/gamma/beta (4 x 3 KB) staged in LDS per block.
//  - removes the type row (3 KB/token) and gamma/beta from the saturated
//    L1 read port (tables+word remain: 15 KB/token),
//  - frees the 24-VGPR gamma/beta register cache -> VGPR ~90 -> 5 waves/SIMD.
// __launch_bounds__(256,4): cap 128, never force down (R7: forcing spills).
// ---------------------------------------------------------------------------
__global__ __launch_bounds__(256, 4) void emb_ln_kernel(
    const int*     __restrict__ ids,       // (B*N)
    const int*     __restrict__ svec,      // (B*N, 3)
    const int*     __restrict__ tt,        // (B*N)
    const float*   __restrict__ word_emb,  // (VOCAB, HIDDEN)
    const float*   __restrict__ type_emb,  // (2, HIDDEN)
    const float*   __restrict__ gamma,     // (HIDDEN)
    const float*   __restrict__ beta,      // (HIDDEN)
    const __half2* __restrict__ T,         // (N_HI+N_LO, NPAIR) f16 (sin,cos)
    float*         __restrict__ out,       // (B*N, HIDDEN)
    int n_tokens)
{
    // LDS: [0..191] type0, [192..383] type1, [384..575] gamma, [576..767] beta
    __shared__ float4 sm[4 * (HIDDEN / 4)];          // 12,288 B

    {
        const float4* t4 = reinterpret_cast<const float4*>(type_emb);
        const float4* g4 = reinterpret_cast<const float4*>(gamma);
        const float4* b4 = reinterpret_cast<const float4*>(beta);
        for (int i = threadIdx.x; i < HIDDEN / 4; i += 256) {
            sm[i]                    = t4[i];
            sm[(HIDDEN / 4) + i]     = t4[(HIDDEN / 4) + i];
            sm[2 * (HIDDEN / 4) + i] = g4[i];
            sm[3 * (HIDDEN / 4) + i] = b4[i];
        }
    }
    __syncthreads();

    const int wave = threadIdx.x >> 6;
    const int lane = threadIdx.x & 63;
    const int nw   = NBLK * 4;                        // total waves in grid
    int tu = __builtin_amdgcn_readfirstlane(blockIdx.x * 4 + wave);
    if (tu >= n_tokens) return;

    // ---- current token indices (SGPR via wave-uniform address) ----
    int id = ids[tu], ty = tt[tu];
    int p0 = svec[3 * tu], p1 = svec[3 * tu + 1], p2 = svec[3 * tu + 2];

    for (;;) {
        const int n = tu & (SEQ_N - 1);               // position within sequence

        const float4* wrow = reinterpret_cast<const float4*>(word_emb + (size_t)id * HIDDEN);
        const float4* trow = &sm[ty * (HIDDEN / 4)];  // LDS type row

        #define T1ROW(p) reinterpret_cast<const h4v*>(T + (size_t)((p) >> 6) * NPAIR)
        #define T2ROW(p) reinterpret_cast<const h4v*>(T + (size_t)(N_HI + ((p) & 63)) * NPAIR)
        const h4v* A0 = T1ROW(n),  *B0 = T2ROW(n);
        const h4v* A1 = T1ROW(p0), *B1 = T2ROW(p0);
        const h4v* A2 = T1ROW(p1), *B2 = T2ROW(p1);
        const h4v* A3 = T1ROW(p2), *B3 = T2ROW(p2);
        #undef T1ROW
        #undef T2ROW

        // prefetch next token's indices into SGPRs (overlaps with compute)
        const int tnext = tu + nw;                    // wave-uniform
        const bool more = tnext < n_tokens;
        int id_n = 0, ty_n = 0, q0 = 0, q1 = 0, q2 = 0;
        if (more) {
            id_n = ids[tnext]; ty_n = tt[tnext];
            q0 = svec[3 * tnext]; q1 = svec[3 * tnext + 1]; q2 = svec[3 * tnext + 2];
        }

        float4 acc[3];
        float s = 0.0f, ss = 0.0f;

        #pragma unroll
        for (int k = 0; k < 3; ++k) {
            const int d4 = lane + 64 * k;

            float4 w = wrow[d4];
            float4 t = trow[d4];                      // ds_read_b128
            h4v a0 = A0[d4], b0 = B0[d4];
            h4v a1 = A1[d4], b1 = B1[d4];
            h4v a2 = A2[d4], b2 = B2[d4];
            h4v a3 = A3[d4], b3 = B3[d4];

            float4 x;
            x.x = w.x + t.x; x.y = w.y + t.y; x.z = w.z + t.z; x.w = w.w + t.w;
            pe_acc(x, a0, b0);
            pe_acc(x, a1, b1);
            pe_acc(x, a2, b2);
            pe_acc(x, a3, b3);

            acc[k] = x;
            s  += x.x + x.y + x.z + x.w;
            ss += x.x * x.x + x.y * x.y + x.z * x.z + x.w * x.w;
        }

        #pragma unroll
        for (int off = 1; off < 64; off <<= 1) {
            s  += __shfl_xor(s,  off);
            ss += __shfl_xor(ss, off);
        }

        const float mean = s * (1.0f / (float)HIDDEN);
        const float var  = ss * (1.0f / (float)HIDDEN) - mean * mean;
        const float inv  = rsqrtf(var + LN_EPS);

        f4v* orow = reinterpret_cast<f4v*>(out + (size_t)tu * HIDDEN);
        #pragma unroll
        for (int k = 0; k < 3; ++k) {
            const int d4 = lane + 64 * k;
            const float4 x = acc[k];
            const float4 g = sm[2 * (HIDDEN / 4) + d4];   // LDS gamma
            const float4 b = sm[3 * (HIDDEN / 4) + d4];   // LDS beta
            f4v r;
            r.x = (x.x - mean) * inv * g.x + b.x;
            r.y = (x.y - mean) * inv * g.y + b.y;
            r.z = (x.z - mean) * inv * g.z + b.z;
            r.w = (x.w - mean) * inv * g.w + b.w;
            __builtin_nontemporal_store(r, &orow[d4]);
        }

        if (!more) break;
        tu = tnext; id = id_n; ty = ty_n; p0 = q0; p1 = q1; p2 = q2;
    }
}

extern "C" void kernel_launch(void* const* d_in, const int* in_sizes, int n_in,
                              void* d_out, int out_size, void* d_ws, size_t ws_size,
                              hipStream_t stream) {
    const int*   ids      = (const int*)d_in[0];   // input_ids      (B*N)
    const int*   svec     = (const int*)d_in[1];   // tok_struct_vec (B*N*3)
    const int*   tt       = (const int*)d_in[2];   // token_type_ids (B*N)
    const float* word_emb = (const float*)d_in[3]; // (VOCAB, HIDDEN)
    const float* type_emb = (const float*)d_in[4]; // (2, HIDDEN)
    const float* gamma    = (const float*)d_in[5]; // (HIDDEN)
    const float* beta     = (const float*)d_in[6]; // (HIDDEN)
    float*       out      = (float*)d_out;

    const int n_tokens = in_sizes[0];

    // Workspace: 144 rows x 384 __half2 = 221 KB.
    __half2* T = (__half2*)d_ws;
    const int total_tab = (N_HI + N_LO) * NPAIR;
    pe_tables_kernel<<<(total_tab + 255) / 256, 256, 0, stream>>>(T);
    emb_ln_kernel<<<NBLK, 256, 0, stream>>>(
        ids, svec, tt, word_emb, type_emb, gamma, beta, T, out, n_tokens);
}

// Round 12
// 44.944 us; speedup vs baseline: 2.6802x; 1.0443x over previous
//
#include <hip/hip_runtime.h>
#include <hip/hip_fp16.h>
#include <cstdint>
#include <cmath>

#define HIDDEN   768
#define NPAIR    (HIDDEN / 2)      // 384 (sin,cos) pairs per row
#define SEQ_N    4096
#define LN_EPS   1e-12f
#define N_T1     313               // ceil(5008/16): angle = 16*hi*d_i
#define N_T2     16                // angle = lo*d_i, lo = p & 15
#define NBLK     2048              // grid-stride: 4 tokens per wave at B*N=32768

typedef float    f4v __attribute__((ext_vector_type(4)));
typedef _Float16 h4v __attribute__((ext_vector_type(4)));

// ---------------------------------------------------------------------------
// Kernel 1: build the two angle-addition tables in d_ws as f16 (sin,cos).
//   T1[hi][i] = (sin,cos)(16*hi * d_i)   hi in [0,313)   — 481 KB, L2-resident
//   T2[lo][i] = (sin,cos)(lo    * d_i)   lo in [0,16)    — 24.6 KB -> LDS
// d_i = exp(-2i * ln(10000)/HIDDEN).  pe[p] = sin/cos(A+B) with A = 16*(p>>4),
// B = p&15 — two-level f16 rotation (~5e-4 abs error, same chain as R11).
// ---------------------------------------------------------------------------
__global__ __launch_bounds__(256) void pe_tables_kernel(__half2* __restrict__ T) {
    const int total = (N_T1 + N_T2) * NPAIR;
    int idx = blockIdx.x * 256 + threadIdx.x;
    if (idx >= total) return;
    int r = idx / NPAIR;
    int i = idx % NPAIR;
    const float L = logf(10000.0f) / (float)HIDDEN;
    float div = expf(-2.0f * (float)i * L);
    int p = (r < N_T1) ? (r << 4) : (r - N_T1);
    float s, c;
    sincosf((float)p * div, &s, &c);
    T[idx] = __floats2half2_rn(s, c);     // x = sin, y = cos
}

// sin(A+B) = sA*cB + cA*sB ; cos(A+B) = cA*cB - sA*sB
// a = (sinA0, cosA0, sinA1, cosA1), b = (sinB0, cosB0, sinB1, cosB1)  [f16]
__device__ __forceinline__ void pe_acc(float4& x, const h4v a, const h4v b) {
    const float sA0 = (float)a.x, cA0 = (float)a.y, sA1 = (float)a.z, cA1 = (float)a.w;
    const float sB0 = (float)b.x, cB0 = (float)b.y, sB1 = (float)b.z, cB1 = (float)b.w;
    x.x = fmaf(sA0, cB0, fmaf(cA0, sB0, x.x));
    x.y = fmaf(cA0, cB0, fmaf(-sA0, sB0, x.y));
    x.z = fmaf(sA1, cB1, fmaf(cA1, sB1, x.z));
    x.w = fmaf(cA1, cB1, fmaf(-sA1, sB1, x.w));
}

// ---------------------------------------------------------------------------
// Kernel 2: fused embedding-sum + LayerNorm.  One 64-lane wave per token,
// grid-strided 4 tokens/wave (2048 blocks), SGPR index prefetch.
// R12: re-split p = 16*hi + lo.  T2 (16 rows, 24.6 KB) staged in LDS ->
// per-token L1 read bytes drop 15 KB -> 9 KB (word 3 + T1 6); the 4 low-
// rotation reads move to the idle LDS pipe (2-way aliasing = free).
// LDS/block = 36.9 KB -> 4 blocks/CU at 256 thr — occupancy unchanged.
// __launch_bounds__(256,4): cap 128, never force down (R7: forcing spills).
// ---------------------------------------------------------------------------
__global__ __launch_bounds__(256, 4) void emb_ln_kernel(
    const int*     __restrict__ ids,       // (B*N)
    const int*     __restrict__ svec,      // (B*N, 3)
    const int*     __restrict__ tt,        // (B*N)
    const float*   __restrict__ word_emb,  // (VOCAB, HIDDEN)
    const float*   __restrict__ type_emb,  // (2, HIDDEN)
    const float*   __restrict__ gamma,     // (HIDDEN)
    const float*   __restrict__ beta,      // (HIDDEN)
    const __half2* __restrict__ T,         // T1 | T2 f16 (sin,cos) tables
    float*         __restrict__ out,       // (B*N, HIDDEN)
    int n_tokens)
{
    // LDS: T2 (16 rows x 384 half2 = 24576 B) + type0/type1/gamma/beta (12288 B)
    __shared__ __align__(16) __half2 sT2[N_T2 * NPAIR];
    __shared__ float4 sm[4 * (HIDDEN / 4)];

    {
        const uint4* src = reinterpret_cast<const uint4*>(T + (size_t)N_T1 * NPAIR);
        uint4*       dst = reinterpret_cast<uint4*>(sT2);
        for (int i = threadIdx.x; i < N_T2 * NPAIR / 4; i += 256) dst[i] = src[i];

        const float4* t4 = reinterpret_cast<const float4*>(type_emb);
        const float4* g4 = reinterpret_cast<const float4*>(gamma);
        const float4* b4 = reinterpret_cast<const float4*>(beta);
        for (int i = threadIdx.x; i < HIDDEN / 4; i += 256) {
            sm[i]                    = t4[i];
            sm[(HIDDEN / 4) + i]     = t4[(HIDDEN / 4) + i];
            sm[2 * (HIDDEN / 4) + i] = g4[i];
            sm[3 * (HIDDEN / 4) + i] = b4[i];
        }
    }
    __syncthreads();

    const int wave = threadIdx.x >> 6;
    const int lane = threadIdx.x & 63;
    const int nw   = NBLK * 4;                        // total waves in grid
    int tu = __builtin_amdgcn_readfirstlane(blockIdx.x * 4 + wave);
    if (tu >= n_tokens) return;

    // ---- current token indices (SGPR via wave-uniform address) ----
    int id = ids[tu], ty = tt[tu];
    int p0 = svec[3 * tu], p1 = svec[3 * tu + 1], p2 = svec[3 * tu + 2];

    for (;;) {
        const int n = tu & (SEQ_N - 1);               // position within sequence

        const float4* wrow = reinterpret_cast<const float4*>(word_emb + (size_t)id * HIDDEN);
        const float4* trow = &sm[ty * (HIDDEN / 4)];  // LDS type row

        // hi rotation rows from global (L1/L2), lo rotation rows from LDS
        #define T1ROW(p) reinterpret_cast<const h4v*>(T + (size_t)((p) >> 4) * NPAIR)
        #define T2ROW(p) reinterpret_cast<const h4v*>(sT2 + ((p) & 15) * NPAIR)
        const h4v* A0 = T1ROW(n),  *B0 = T2ROW(n);
        const h4v* A1 = T1ROW(p0), *B1 = T2ROW(p0);
        const h4v* A2 = T1ROW(p1), *B2 = T2ROW(p1);
        const h4v* A3 = T1ROW(p2), *B3 = T2ROW(p2);
        #undef T1ROW
        #undef T2ROW

        // prefetch next token's indices into SGPRs (overlaps with compute)
        const int tnext = tu + nw;                    // wave-uniform
        const bool more = tnext < n_tokens;
        int id_n = 0, ty_n = 0, q0 = 0, q1 = 0, q2 = 0;
        if (more) {
            id_n = ids[tnext]; ty_n = tt[tnext];
            q0 = svec[3 * tnext]; q1 = svec[3 * tnext + 1]; q2 = svec[3 * tnext + 2];
        }

        float4 acc[3];
        float s = 0.0f, ss = 0.0f;

        #pragma unroll
        for (int k = 0; k < 3; ++k) {
            const int d4 = lane + 64 * k;

            float4 w = wrow[d4];
            float4 t = trow[d4];                      // ds_read_b128
            h4v a0 = A0[d4], b0 = B0[d4];             // global 8B + LDS 8B
            h4v a1 = A1[d4], b1 = B1[d4];
            h4v a2 = A2[d4], b2 = B2[d4];
            h4v a3 = A3[d4], b3 = B3[d4];

            float4 x;
            x.x = w.x + t.x; x.y = w.y + t.y; x.z = w.z + t.z; x.w = w.w + t.w;
            pe_acc(x, a0, b0);
            pe_acc(x, a1, b1);
            pe_acc(x, a2, b2);
            pe_acc(x, a3, b3);

            acc[k] = x;
            s  += x.x + x.y + x.z + x.w;
            ss += x.x * x.x + x.y * x.y + x.z * x.z + x.w * x.w;
        }

        #pragma unroll
        for (int off = 1; off < 64; off <<= 1) {
            s  += __shfl_xor(s,  off);
            ss += __shfl_xor(ss, off);
        }

        const float mean = s * (1.0f / (float)HIDDEN);
        const float var  = ss * (1.0f / (float)HIDDEN) - mean * mean;
        const float inv  = rsqrtf(var + LN_EPS);

        f4v* orow = reinterpret_cast<f4v*>(out + (size_t)tu * HIDDEN);
        #pragma unroll
        for (int k = 0; k < 3; ++k) {
            const int d4 = lane + 64 * k;
            const float4 x = acc[k];
            const float4 g = sm[2 * (HIDDEN / 4) + d4];   // LDS gamma
            const float4 b = sm[3 * (HIDDEN / 4) + d4];   // LDS beta
            f4v r;
            r.x = (x.x - mean) * inv * g.x + b.x;
            r.y = (x.y - mean) * inv * g.y + b.y;
            r.z = (x.z - mean) * inv * g.z + b.z;
            r.w = (x.w - mean) * inv * g.w + b.w;
            __builtin_nontemporal_store(r, &orow[d4]);
        }

        if (!more) break;
        tu = tnext; id = id_n; ty = ty_n; p0 = q0; p1 = q1; p2 = q2;
    }
}

extern "C" void kernel_launch(void* const* d_in, const int* in_sizes, int n_in,
                              void* d_out, int out_size, void* d_ws, size_t ws_size,
                              hipStream_t stream) {
    const int*   ids      = (const int*)d_in[0];   // input_ids      (B*N)
    const int*   svec     = (const int*)d_in[1];   // tok_struct_vec (B*N*3)
    const int*   tt       = (const int*)d_in[2];   // token_type_ids (B*N)
    const float* word_emb = (const float*)d_in[3]; // (VOCAB, HIDDEN)
    const float* type_emb = (const float*)d_in[4]; // (2, HIDDEN)
    const float* gamma    = (const float*)d_in[5]; // (HIDDEN)
    const float* beta     = (const float*)d_in[6]; // (HIDDEN)
    float*       out      = (float*)d_out;

    const int n_tokens = in_sizes[0];

    // Workspace: (313 + 16) rows x 384 __half2 = 506 KB.
    __half2* T = (__half2*)d_ws;
    const int total_tab = (N_T1 + N_T2) * NPAIR;
    pe_tables_kernel<<<(total_tab + 255) / 256, 256, 0, stream>>>(T);
    emb_ln_kernel<<<NBLK, 256, 0, stream>>>(
        ids, svec, tt, word_emb, type_emb, gamma, beta, T, out, n_tokens);
}

// Round 13
// 44.152 us; speedup vs baseline: 2.7283x; 1.0179x over previous
//
#include <hip/hip_runtime.h>
#include <hip/hip_fp16.h>
#include <cstdint>
#include <cmath>

#define HIDDEN   768
#define NPAIR    (HIDDEN / 2)      // 384 (sin,cos) pairs per row
#define SEQ_N    4096
#define LN_EPS   1e-12f
#define N_T1     313               // ceil(5008/16): angle = 16*hi*d_i
#define N_T2     16                // angle = lo*d_i, lo = p & 15
#define NBLK     2048              // grid-stride: 4 tokens per wave at B*N=32768
// NOTE: wave stride = NBLK*4 = 8192 tokens; 8192 % SEQ_N == 0, so a wave's
// tokens all share the same sequence position n = tu & (SEQ_N-1).

typedef float    f4v __attribute__((ext_vector_type(4)));
typedef _Float16 h4v __attribute__((ext_vector_type(4)));

// ---------------------------------------------------------------------------
// Kernel 1: build the two angle-addition tables in d_ws as f16 (sin,cos).
//   T1[hi][i] = (sin,cos)(16*hi * d_i)   hi in [0,313)   — 481 KB, L2-resident
//   T2[lo][i] = (sin,cos)(lo    * d_i)   lo in [0,16)    — 24.6 KB -> LDS
// d_i = exp(-2i * ln(10000)/HIDDEN).  pe[p] = sin/cos(A+B), A = 16*(p>>4),
// B = p&15 — two-level f16 rotation (~5e-4 abs error).
// ---------------------------------------------------------------------------
__global__ __launch_bounds__(256) void pe_tables_kernel(__half2* __restrict__ T) {
    const int total = (N_T1 + N_T2) * NPAIR;
    int idx = blockIdx.x * 256 + threadIdx.x;
    if (idx >= total) return;
    int r = idx / NPAIR;
    int i = idx % NPAIR;
    const float L = logf(10000.0f) / (float)HIDDEN;
    float div = expf(-2.0f * (float)i * L);
    int p = (r < N_T1) ? (r << 4) : (r - N_T1);
    float s, c;
    sincosf((float)p * div, &s, &c);
    T[idx] = __floats2half2_rn(s, c);     // x = sin, y = cos
}

// sin(A+B) = sA*cB + cA*sB ; cos(A+B) = cA*cB - sA*sB
// a = (sinA0, cosA0, sinA1, cosA1), b = (sinB0, cosB0, sinB1, cosB1)  [f16]
__device__ __forceinline__ void pe_acc(float4& x, const h4v a, const h4v b) {
    const float sA0 = (float)a.x, cA0 = (float)a.y, sA1 = (float)a.z, cA1 = (float)a.w;
    const float sB0 = (float)b.x, cB0 = (float)b.y, sB1 = (float)b.z, cB1 = (float)b.w;
    x.x = fmaf(sA0, cB0, fmaf(cA0, sB0, x.x));
    x.y = fmaf(cA0, cB0, fmaf(-sA0, sB0, x.y));
    x.z = fmaf(sA1, cB1, fmaf(cA1, sB1, x.z));
    x.w = fmaf(cA1, cB1, fmaf(-sA1, sB1, x.w));
}

// ---------------------------------------------------------------------------
// Kernel 2: fused embedding-sum + LayerNorm.  One 64-lane wave per token,
// grid-strided 4 tokens/wave (2048 blocks), SGPR index prefetch, T2 +
// type/gamma/beta in LDS (R11/R12).
// R13: the wave's grid-stride (8192) is a multiple of SEQ_N (4096), so the
// sequence position n — and hence the positional-PE row — is wave-invariant.
// Reconstruct posPE once before the loop (12 f32 regs) and drop to 3
// rotations per token: saves ~1.1 KB/token of T1 L1 reads, 3 LDS row reads
// and 24 FMAs per iteration.  +12 VGPR, still under the (256,4) cap of 128
// (R7: never force the cap down — spills are catastrophic).
// ---------------------------------------------------------------------------
__global__ __launch_bounds__(256, 4) void emb_ln_kernel(
    const int*     __restrict__ ids,       // (B*N)
    const int*     __restrict__ svec,      // (B*N, 3)
    const int*     __restrict__ tt,        // (B*N)
    const float*   __restrict__ word_emb,  // (VOCAB, HIDDEN)
    const float*   __restrict__ type_emb,  // (2, HIDDEN)
    const float*   __restrict__ gamma,     // (HIDDEN)
    const float*   __restrict__ beta,      // (HIDDEN)
    const __half2* __restrict__ T,         // T1 | T2 f16 (sin,cos) tables
    float*         __restrict__ out,       // (B*N, HIDDEN)
    int n_tokens)
{
    // LDS: T2 (16 rows x 384 half2 = 24576 B) + type0/type1/gamma/beta (12288 B)
    __shared__ __align__(16) __half2 sT2[N_T2 * NPAIR];
    __shared__ float4 sm[4 * (HIDDEN / 4)];

    {
        const uint4* src = reinterpret_cast<const uint4*>(T + (size_t)N_T1 * NPAIR);
        uint4*       dst = reinterpret_cast<uint4*>(sT2);
        for (int i = threadIdx.x; i < N_T2 * NPAIR / 4; i += 256) dst[i] = src[i];

        const float4* t4 = reinterpret_cast<const float4*>(type_emb);
        const float4* g4 = reinterpret_cast<const float4*>(gamma);
        const float4* b4 = reinterpret_cast<const float4*>(beta);
        for (int i = threadIdx.x; i < HIDDEN / 4; i += 256) {
            sm[i]                    = t4[i];
            sm[(HIDDEN / 4) + i]     = t4[(HIDDEN / 4) + i];
            sm[2 * (HIDDEN / 4) + i] = g4[i];
            sm[3 * (HIDDEN / 4) + i] = b4[i];
        }
    }
    __syncthreads();

    const int wave = threadIdx.x >> 6;
    const int lane = threadIdx.x & 63;
    const int nw   = NBLK * 4;                        // total waves in grid
    int tu = __builtin_amdgcn_readfirstlane(blockIdx.x * 4 + wave);
    if (tu >= n_tokens) return;

    #define T1ROW(p) reinterpret_cast<const h4v*>(T + (size_t)((p) >> 4) * NPAIR)
    #define T2ROW(p) reinterpret_cast<const h4v*>(sT2 + ((p) & 15) * NPAIR)

    // ---- wave-invariant positional PE, reconstructed once ----
    const int n = tu & (SEQ_N - 1);
    float4 posPE[3];
    {
        const h4v* An = T1ROW(n);
        const h4v* Bn = T2ROW(n);
        #pragma unroll
        for (int k = 0; k < 3; ++k) {
            const int d4 = lane + 64 * k;
            posPE[k] = make_float4(0.f, 0.f, 0.f, 0.f);
            pe_acc(posPE[k], An[d4], Bn[d4]);
        }
    }

    // ---- current token indices (SGPR via wave-uniform address) ----
    int id = ids[tu], ty = tt[tu];
    int p0 = svec[3 * tu], p1 = svec[3 * tu + 1], p2 = svec[3 * tu + 2];

    for (;;) {
        const float4* wrow = reinterpret_cast<const float4*>(word_emb + (size_t)id * HIDDEN);
        const float4* trow = &sm[ty * (HIDDEN / 4)];  // LDS type row

        const h4v* A1 = T1ROW(p0), *B1 = T2ROW(p0);
        const h4v* A2 = T1ROW(p1), *B2 = T2ROW(p1);
        const h4v* A3 = T1ROW(p2), *B3 = T2ROW(p2);

        // prefetch next token's indices into SGPRs (overlaps with compute)
        const int tnext = tu + nw;                    // wave-uniform
        const bool more = tnext < n_tokens;
        int id_n = 0, ty_n = 0, q0 = 0, q1 = 0, q2 = 0;
        if (more) {
            id_n = ids[tnext]; ty_n = tt[tnext];
            q0 = svec[3 * tnext]; q1 = svec[3 * tnext + 1]; q2 = svec[3 * tnext + 2];
        }

        float4 acc[3];
        float s = 0.0f, ss = 0.0f;

        #pragma unroll
        for (int k = 0; k < 3; ++k) {
            const int d4 = lane + 64 * k;

            float4 w = wrow[d4];
            float4 t = trow[d4];                      // ds_read_b128
            h4v a1 = A1[d4], b1 = B1[d4];             // global 8B + LDS 8B
            h4v a2 = A2[d4], b2 = B2[d4];
            h4v a3 = A3[d4], b3 = B3[d4];

            float4 x;
            x.x = w.x + t.x + posPE[k].x;
            x.y = w.y + t.y + posPE[k].y;
            x.z = w.z + t.z + posPE[k].z;
            x.w = w.w + t.w + posPE[k].w;
            pe_acc(x, a1, b1);
            pe_acc(x, a2, b2);
            pe_acc(x, a3, b3);

            acc[k] = x;
            s  += x.x + x.y + x.z + x.w;
            ss += x.x * x.x + x.y * x.y + x.z * x.z + x.w * x.w;
        }

        #pragma unroll
        for (int off = 1; off < 64; off <<= 1) {
            s  += __shfl_xor(s,  off);
            ss += __shfl_xor(ss, off);
        }

        const float mean = s * (1.0f / (float)HIDDEN);
        const float var  = ss * (1.0f / (float)HIDDEN) - mean * mean;
        const float inv  = rsqrtf(var + LN_EPS);

        f4v* orow = reinterpret_cast<f4v*>(out + (size_t)tu * HIDDEN);
        #pragma unroll
        for (int k = 0; k < 3; ++k) {
            const int d4 = lane + 64 * k;
            const float4 x = acc[k];
            const float4 g = sm[2 * (HIDDEN / 4) + d4];   // LDS gamma
            const float4 b = sm[3 * (HIDDEN / 4) + d4];   // LDS beta
            f4v r;
            r.x = (x.x - mean) * inv * g.x + b.x;
            r.y = (x.y - mean) * inv * g.y + b.y;
            r.z = (x.z - mean) * inv * g.z + b.z;
            r.w = (x.w - mean) * inv * g.w + b.w;
            __builtin_nontemporal_store(r, &orow[d4]);
        }

        if (!more) break;
        tu = tnext; id = id_n; ty = ty_n; p0 = q0; p1 = q1; p2 = q2;
    }
    #undef T1ROW
    #undef T2ROW
}

extern "C" void kernel_launch(void* const* d_in, const int* in_sizes, int n_in,
                              void* d_out, int out_size, void* d_ws, size_t ws_size,
                              hipStream_t stream) {
    const int*   ids      = (const int*)d_in[0];   // input_ids      (B*N)
    const int*   svec     = (const int*)d_in[1];   // tok_struct_vec (B*N*3)
    const int*   tt       = (const int*)d_in[2];   // token_type_ids (B*N)
    const float* word_emb = (const float*)d_in[3]; // (VOCAB, HIDDEN)
    const float* type_emb = (const float*)d_in[4]; // (2, HIDDEN)
    const float* gamma    = (const float*)d_in[5]; // (HIDDEN)
    const float* beta     = (const float*)d_in[6]; // (HIDDEN)
    float*       out      = (float*)d_out;

    const int n_tokens = in_sizes[0];

    // Workspace: (313 + 16) rows x 384 __half2 = 506 KB.
    __half2* T = (__half2*)d_ws;
    const int total_tab = (N_T1 + N_T2) * NPAIR;
    pe_tables_kernel<<<(total_tab + 255) / 256, 256, 0, stream>>>(T);
    emb_ln_kernel<<<NBLK, 256, 0, stream>>>(
        ids, svec, tt, word_emb, type_emb, gamma, beta, T, out, n_tokens);
}